// Round 5
// baseline (167.383 us; speedup 1.0000x reference)
//
#include <hip/hip_runtime.h>
#include <hip/hip_bf16.h>

#define ROWS   8192
#define DIM    512
#define NCODES 8192
#define BM     256
#define BN     256
#define BK     32
#define NT     (DIM / BK)             // 16 K-tiles
#define MARGIN 0.75f

using bf16x8 = __attribute__((ext_vector_type(8))) short;
using f32x4  = __attribute__((ext_vector_type(4))) float;
typedef unsigned short ushort_t;

__device__ __forceinline__ void gload_lds16(const void* g, void* l) {
    __builtin_amdgcn_global_load_lds((const __attribute__((address_space(1))) void*)g,
                                     (__attribute__((address_space(3))) void*)l,
                                     16, 0, 0);
}

__device__ __forceinline__ unsigned short f2bf_rne(float f) {
    unsigned int u = __float_as_uint(f);
    u = (u + 0x7FFFu + ((u >> 16) & 1u)) >> 16;
    return (unsigned short)u;
}

// ---------- Kernel 1: LN stats + bf16(h) rows, and bf16(embd) rows ----------
__global__ __launch_bounds__(256) void prep_kernel(
    const float* __restrict__ x, const float* __restrict__ lw,
    const float* __restrict__ lb, const float* __restrict__ embd,
    float2* __restrict__ stats, ushort_t* __restrict__ Hb,
    ushort_t* __restrict__ Eb)
{
    const int w    = threadIdx.x >> 6;
    const int lane = threadIdx.x & 63;
    const int b    = blockIdx.x;

    if (b < 2048) {
        const int row = b * 4 + w;
        const float* xr = x + (size_t)row * DIM + lane * 8;
        float4 v0 = *(const float4*)(xr);
        float4 v1 = *(const float4*)(xr + 4);
        float s = (v0.x + v0.y) + (v0.z + v0.w) + (v1.x + v1.y) + (v1.z + v1.w);
        float q = v0.x*v0.x + v0.y*v0.y + v0.z*v0.z + v0.w*v0.w
                + v1.x*v1.x + v1.y*v1.y + v1.z*v1.z + v1.w*v1.w;
        #pragma unroll
        for (int off = 1; off < 64; off <<= 1) {
            s += __shfl_xor(s, off);
            q += __shfl_xor(q, off);
        }
        float mu   = s * (1.0f / DIM);
        float var  = q * (1.0f / DIM) - mu * mu;
        float rstd = rsqrtf(var + 1e-5f);
        if (lane == 0) stats[row] = make_float2(mu, rstd);

        float4 w0 = *(const float4*)(lw + lane * 8);
        float4 w1 = *(const float4*)(lw + lane * 8 + 4);
        float4 b0 = *(const float4*)(lb + lane * 8);
        float4 b1 = *(const float4*)(lb + lane * 8 + 4);
        float hv[8] = {
            (v0.x - mu) * rstd * w0.x + b0.x, (v0.y - mu) * rstd * w0.y + b0.y,
            (v0.z - mu) * rstd * w0.z + b0.z, (v0.w - mu) * rstd * w0.w + b0.w,
            (v1.x - mu) * rstd * w1.x + b1.x, (v1.y - mu) * rstd * w1.y + b1.y,
            (v1.z - mu) * rstd * w1.z + b1.z, (v1.w - mu) * rstd * w1.w + b1.w };
        union { unsigned short u[8]; uint4 v; } p;
        #pragma unroll
        for (int j = 0; j < 8; ++j) p.u[j] = f2bf_rne(hv[j]);
        *(uint4*)(Hb + (size_t)row * DIM + lane * 8) = p.v;
    } else {
        const int row = (b - 2048) * 4 + w;
        const float* er = embd + (size_t)row * DIM + lane * 8;
        float4 v0 = *(const float4*)(er);
        float4 v1 = *(const float4*)(er + 4);
        float ev[8] = { v0.x, v0.y, v0.z, v0.w, v1.x, v1.y, v1.z, v1.w };
        union { unsigned short u[8]; uint4 v; } p;
        #pragma unroll
        for (int j = 0; j < 8; ++j) p.u[j] = f2bf_rne(ev[j]);
        *(uint4*)(Eb + (size_t)row * DIM + lane * 8) = p.v;
    }
}

// ---------- Kernel 2: 256x256 bf16 MFMA GEMM, 2-phase-per-K-tile interleave --
// 512 threads = 8 waves (2 row-halves x 4 col-quarters). Per-wave output 128x64.
// LDS: 4 ring slots x (A 16KB + B 16KB) = 128KB. T2 swizzle byte^=((row>>1)&3)<<4.
// Phase template (m201): {ds_read subtile || 1 half-stage -> bar -> prio1 16 MFMA
// prio0 -> bar}; counted vmcnt once per K-tile (6,...,6,4,0), never drained mid-loop.
// Stage stream: ph0 of t stages B(t+2); ph1 of t stages A(t+3) => at each K-tile
// end the newest-6 outstanding are {A(t+3),B(t+2),A(t+2)}, so vmcnt(6) proves
// tile t+1 fully landed.
__global__ __launch_bounds__(512, 2) void gemm_argmax_kernel(
    const ushort_t* __restrict__ Hb, const ushort_t* __restrict__ Eb,
    float* __restrict__ pval, int* __restrict__ pidx)
{
    __shared__ __align__(16) ushort_t As[4][BM * BK];
    __shared__ __align__(16) ushort_t Bs[4][BN * BK];

    const int t    = threadIdx.x;
    const int w    = t >> 6;
    const int lane = t & 63;
    const int r_   = lane & 15;
    const int g    = lane >> 4;
    const int wr   = w >> 2;          // row half (0,1)
    const int wc   = w & 3;           // col quarter (0..3)

    // T1: XCD-region remap (XCD = bid % 8 owns 4 tile-rows, col-major order)
    const int bid  = blockIdx.x;
    const int slot = bid >> 3;
    const int trow = ((bid & 7) << 2) | (slot & 3);
    const int tcol = slot >> 2;
    const int r0 = trow * BM;
    const int n0 = tcol * BN;

    // staging geometry: wave w covers rows w*32..w*32+31 via 2 gload_lds per
    // operand. dest byte d = j*1024 + lane*16 -> drow=j*16+(lane>>2),
    // dcol=(lane&3)*16; inverse-swizzled SOURCE col byte = dcol ^ ((drow>>1)&3)<<4.
    const int arow0 = w * 32 + (lane >> 2);
    const int arow1 = arow0 + 16;
    const int lcb0  = ((lane & 3) * 16) ^ (((arow0 >> 1) & 3) << 4);
    const int lcb1  = ((lane & 3) * 16) ^ (((arow1 >> 1) & 3) << 4);
    const ushort_t* srcA0 = Hb + (size_t)(r0 + arow0) * DIM + (lcb0 >> 1);
    const ushort_t* srcA1 = Hb + (size_t)(r0 + arow1) * DIM + (lcb1 >> 1);
    const ushort_t* srcB0 = Eb + (size_t)(n0 + arow0) * DIM + (lcb0 >> 1);
    const ushort_t* srcB1 = Eb + (size_t)(n0 + arow1) * DIM + (lcb1 >> 1);
    const int j0u = (w * 2) * 512;
    const int j1u = (w * 2 + 1) * 512;

    // swizzled ds_read bases (byte offsets within a slot)
    const int swz   = ((r_ >> 1) & 3) << 4;
    const int abase = (wr * 128 + r_) * 64 + ((g * 16) ^ swz);   // + m*1024
    const int bbase = (wc * 64  + r_) * 64 + ((g * 16) ^ swz);   // + n*1024

    f32x4 acc[8][4];
    #pragma unroll
    for (int m = 0; m < 8; ++m)
        #pragma unroll
        for (int n = 0; n < 4; ++n) acc[m][n] = (f32x4){0.f, 0.f, 0.f, 0.f};

#define STAGE_A(T) do {                                             \
        const int _ko = (T) * BK;                                   \
        gload_lds16(srcA0 + _ko, &As[(T) & 3][j0u]);                \
        gload_lds16(srcA1 + _ko, &As[(T) & 3][j1u]);                \
    } while (0)
#define STAGE_B(T) do {                                             \
        const int _ko = (T) * BK;                                   \
        gload_lds16(srcB0 + _ko, &Bs[(T) & 3][j0u]);                \
        gload_lds16(srcB1 + _ko, &Bs[(T) & 3][j1u]);                \
    } while (0)
#define MF(M, N, AV, BV) \
        acc[M][N] = __builtin_amdgcn_mfma_f32_16x16x32_bf16(AV, BV, acc[M][N], 0, 0, 0)
#define VMW(N) asm volatile("s_waitcnt vmcnt(" #N ")" ::: "memory")

#define K_TILE(T, DOSB, DOSA, VMCODE) do {                          \
        const char* Ab = (const char*)&As[(T) & 3][0];              \
        const char* Bb = (const char*)&Bs[(T) & 3][0];              \
        /* ---- phase 0: quadrant m0-3 ---- */                      \
        bf16x8 a0 = *(const bf16x8*)(Ab + abase + 0 * 1024);        \
        bf16x8 a1 = *(const bf16x8*)(Ab + abase + 1 * 1024);        \
        bf16x8 a2 = *(const bf16x8*)(Ab + abase + 2 * 1024);        \
        bf16x8 a3 = *(const bf16x8*)(Ab + abase + 3 * 1024);        \
        bf16x8 b0 = *(const bf16x8*)(Bb + bbase + 0 * 1024);        \
        bf16x8 b1 = *(const bf16x8*)(Bb + bbase + 1 * 1024);        \
        bf16x8 b2 = *(const bf16x8*)(Bb + bbase + 2 * 1024);        \
        bf16x8 b3 = *(const bf16x8*)(Bb + bbase + 3 * 1024);        \
        if (DOSB) STAGE_B((T) + 2);                                 \
        __builtin_amdgcn_s_barrier();                               \
        __builtin_amdgcn_s_setprio(1);                              \
        MF(0, 0, a0, b0); MF(0, 1, a0, b1); MF(0, 2, a0, b2); MF(0, 3, a0, b3); \
        MF(1, 0, a1, b0); MF(1, 1, a1, b1); MF(1, 2, a1, b2); MF(1, 3, a1, b3); \
        MF(2, 0, a2, b0); MF(2, 1, a2, b1); MF(2, 2, a2, b2); MF(2, 3, a2, b3); \
        MF(3, 0, a3, b0); MF(3, 1, a3, b1); MF(3, 2, a3, b2); MF(3, 3, a3, b3); \
        __builtin_amdgcn_s_setprio(0);                              \
        __builtin_amdgcn_s_barrier();                               \
        /* ---- phase 1: quadrant m4-7 (b0-3 reused from regs) ---- */ \
        a0 = *(const bf16x8*)(Ab + abase + 4 * 1024);               \
        a1 = *(const bf16x8*)(Ab + abase + 5 * 1024);               \
        a2 = *(const bf16x8*)(Ab + abase + 6 * 1024);               \
        a3 = *(const bf16x8*)(Ab + abase + 7 * 1024);               \
        if (DOSA) STAGE_A((T) + 3);                                 \
        VMCODE;                                                     \
        __builtin_amdgcn_s_barrier();                               \
        __builtin_amdgcn_s_setprio(1);                              \
        MF(4, 0, a0, b0); MF(4, 1, a0, b1); MF(4, 2, a0, b2); MF(4, 3, a0, b3); \
        MF(5, 0, a1, b0); MF(5, 1, a1, b1); MF(5, 2, a1, b2); MF(5, 3, a1, b3); \
        MF(6, 0, a2, b0); MF(6, 1, a2, b1); MF(6, 2, a2, b2); MF(6, 3, a2, b3); \
        MF(7, 0, a3, b0); MF(7, 1, a3, b1); MF(7, 2, a3, b2); MF(7, 3, a3, b3); \
        __builtin_amdgcn_s_setprio(0);                              \
        __builtin_amdgcn_s_barrier();                               \
    } while (0)

    // prologue: stream A0,B0,A1,B1,A2 (10 loads); vmcnt(6) => A0,B0 landed
    STAGE_A(0); STAGE_B(0);
    STAGE_A(1); STAGE_B(1);
    STAGE_A(2);
    VMW(6);
    __builtin_amdgcn_s_barrier();

    K_TILE(0,  1, 1, VMW(6));
    K_TILE(1,  1, 1, VMW(6));
    K_TILE(2,  1, 1, VMW(6));
    K_TILE(3,  1, 1, VMW(6));
    K_TILE(4,  1, 1, VMW(6));
    K_TILE(5,  1, 1, VMW(6));
    K_TILE(6,  1, 1, VMW(6));
    K_TILE(7,  1, 1, VMW(6));
    K_TILE(8,  1, 1, VMW(6));
    K_TILE(9,  1, 1, VMW(6));
    K_TILE(10, 1, 1, VMW(6));
    K_TILE(11, 1, 1, VMW(6));
    K_TILE(12, 1, 1, VMW(6));   // stages B(14), A(15)
    K_TILE(13, 1, 0, VMW(4));   // stages B(15); newest-4 = {B15,A15} -> tile 14 ok
    K_TILE(14, 0, 0, VMW(0));   // drain: tile 15 ready
    K_TILE(15, 0, 0, );

#undef K_TILE
#undef VMW
#undef MF
#undef STAGE_B
#undef STAGE_A

    // ---- epilogue: per-row top-2 over this wave's 64-col chunk ----
    const int cb = n0 + wc * 64;
    #pragma unroll
    for (int m = 0; m < 8; ++m) {
        #pragma unroll
        for (int reg = 0; reg < 4; ++reg) {
            float v1 = acc[m][0][reg]; int i1 = cb + r_;
            float v2 = -3.4e38f;       int i2 = 0;
            #pragma unroll
            for (int n = 1; n < 4; ++n) {
                float vv = acc[m][n][reg];
                int   cc = cb + n * 16 + r_;
                if (vv > v1)      { v2 = v1; i2 = i1; v1 = vv; i1 = cc; }
                else if (vv > v2) { v2 = vv; i2 = cc; }
            }
            #pragma unroll
            for (int off = 1; off < 16; off <<= 1) {
                float u1 = __shfl_xor(v1, off);
                int   j1 = __shfl_xor(i1, off);
                float u2 = __shfl_xor(v2, off);
                int   j2 = __shfl_xor(i2, off);
                if (u1 > v1) {
                    if (v1 > u2) { v2 = v1; i2 = i1; }
                    else         { v2 = u2; i2 = j2; }
                    v1 = u1; i1 = j1;
                } else if (u1 > v2) { v2 = u1; i2 = j1; }
            }
            if (r_ == 0) {
                const int row  = r0 + wr * 128 + m * 16 + g * 4 + reg;
                const size_t base = (size_t)row * 256 + (n0 >> 5) + wc * 2;
                pval[base] = v1; pval[base + 1] = v2;
                pidx[base] = i1; pidx[base + 1] = i2;
            }
        }
    }
}

// ---------- Kernel 3: exact fp32 re-check of candidates + gather ----------
__global__ __launch_bounds__(256) void finalize_kernel(
    const float* __restrict__ x, const float* __restrict__ lw,
    const float* __restrict__ lb, const float* __restrict__ embd,
    const float2* __restrict__ stats,
    const float* __restrict__ pval, const int* __restrict__ pidx,
    float* __restrict__ outq, float* __restrict__ outi)
{
    const int w    = threadIdx.x >> 6;
    const int lane = threadIdx.x & 63;
    const int row  = blockIdx.x * 4 + w;

    const float4 cv = *(const float4*)&pval[(size_t)row * 256 + lane * 4];
    const int4   ci = *(const int4*)  &pidx[(size_t)row * 256 + lane * 4];
    float vv[4] = { cv.x, cv.y, cv.z, cv.w };
    int   ii[4] = { ci.x, ci.y, ci.z, ci.w };

    float M = fmaxf(fmaxf(vv[0], vv[1]), fmaxf(vv[2], vv[3]));
    #pragma unroll
    for (int off = 1; off < 64; off <<= 1) M = fmaxf(M, __shfl_xor(M, off));
    const float T = M - MARGIN;

    const float2 st = stats[row];
    const float mu = st.x, rstd = st.y;
    const float* xr = x + (size_t)row * DIM + lane * 8;
    float4 x0 = *(const float4*)(xr);
    float4 x1 = *(const float4*)(xr + 4);
    float4 w0 = *(const float4*)(lw + lane * 8);
    float4 w1 = *(const float4*)(lw + lane * 8 + 4);
    float4 b0 = *(const float4*)(lb + lane * 8);
    float4 b1 = *(const float4*)(lb + lane * 8 + 4);
    float h[8] = {
        (x0.x - mu) * rstd * w0.x + b0.x, (x0.y - mu) * rstd * w0.y + b0.y,
        (x0.z - mu) * rstd * w0.z + b0.z, (x0.w - mu) * rstd * w0.w + b0.w,
        (x1.x - mu) * rstd * w1.x + b1.x, (x1.y - mu) * rstd * w1.y + b1.y,
        (x1.z - mu) * rstd * w1.z + b1.z, (x1.w - mu) * rstd * w1.w + b1.w };

    float bestv = -3.4e38f; int besti = 0x7fffffff;
    #pragma unroll
    for (int s = 0; s < 4; ++s) {
        unsigned long long msk = __ballot(vv[s] >= T);
        while (msk) {
            const int L = __ffsll(msk) - 1;
            msk &= msk - 1;
            const int cand = __shfl(ii[s], L);
            const float* er = embd + (size_t)cand * DIM + lane * 8;
            float4 e0 = *(const float4*)er;
            float4 e1 = *(const float4*)(er + 4);
            float d = h[0]*e0.x + h[1]*e0.y + h[2]*e0.z + h[3]*e0.w
                    + h[4]*e1.x + h[5]*e1.y + h[6]*e1.z + h[7]*e1.w;
            #pragma unroll
            for (int off = 1; off < 64; off <<= 1) d += __shfl_xor(d, off);
            if (d > bestv || (d == bestv && cand < besti)) { bestv = d; besti = cand; }
        }
    }

    const float* er = embd + (size_t)besti * DIM + lane * 8;
    float4 q0 = *(const float4*)er;
    float4 q1 = *(const float4*)(er + 4);
    float* qr = outq + (size_t)row * DIM + lane * 8;
    *(float4*)(qr)     = q0;
    *(float4*)(qr + 4) = q1;
    if (lane == 0) outi[row] = (float)besti;
}

extern "C" void kernel_launch(void* const* d_in, const int* in_sizes, int n_in,
                              void* d_out, int out_size, void* d_ws, size_t ws_size,
                              hipStream_t stream) {
    const float* x    = (const float*)d_in[0];
    const float* lnw  = (const float*)d_in[1];
    const float* lnb  = (const float*)d_in[2];
    const float* embd = (const float*)d_in[3];

    float* outq = (float*)d_out;
    float* outi = outq + (size_t)ROWS * DIM;

    char* ws = (char*)d_ws;
    float2*   stats = (float2*)ws;                                   // 64 KiB
    ushort_t* Hb    = (ushort_t*)(ws + (1 << 16));                   // 8 MiB
    ushort_t* Eb    = (ushort_t*)(ws + (1 << 16) + (8 << 20));       // 8 MiB
    float*    pval  = (float*)(ws + (1 << 16) + (16 << 20));         // 8 MiB
    int*      pidx  = (int*)  (ws + (1 << 16) + (24 << 20));         // 8 MiB

    prep_kernel<<<4096, 256, 0, stream>>>(x, lnw, lnb, embd, stats, Hb, Eb);

    gemm_argmax_kernel<<<1024, 512, 0, stream>>>(Hb, Eb, pval, pidx);

    finalize_kernel<<<ROWS / 4, 256, 0, stream>>>(x, lnw, lnb, embd, stats,
                                                  pval, pidx, outq, outi);
}